// Round 7
// baseline (260.375 us; speedup 1.0000x reference)
//
#include <hip/hip_runtime.h>

// SSIM loss, fused. R12: R11's register+shuffle kernel (zero LDS, zero
// barriers) re-packed 4 WAVES PER 256-THREAD BLOCK.
// R11 post-mortem: 1-wave (64-thr) blocks cap at ~8 workgroups/CU ->
// occupancy 23% (~1.85 waves/SIMD); every dep chain (prefix->shuffle->SSIM
// ->load wait) was wall-clock exposed: ~17k cy/row vs ~1.6k cy of issue.
// Fix: pack 4 fully-independent waves per block (no shared state, no
// barriers) -> 1024 blocks = 4 blocks/CU x 4 waves = 16 waves/CU resident.
// Math, pipeline, and load schedule IDENTICAL to R11 (absmax 0.0 there):
//  - lane owns 8 adjacent cols (2 float4 loads/img); cs[4][8] in registers;
//  - 11-tap horizontal window = local prefix/suffix sums + 5 shfl_up from
//    lane t-1 + 5 shfl_down from lane t+1, edges via mask-fma;
//  - u=x+y, v=x-y -> Su,Sv,Suu,Svv;
//  - add-row prefetched one iteration ahead; sub-row issued before SSIM
//    math (L3-resident re-read), consumed at iteration end.

#define IMG_H 512
#define IMG_W 512
#define N_IMG 64
#define STRIP 8            // output rows per wave
#define NTHREADS 256       // 4 independent waves per block
#define WPB 4              // waves per block

__global__ __launch_bounds__(NTHREADS, 4) void ssim_kernel(const float* __restrict__ img1,
                                                           const float* __restrict__ img2,
                                                           float* __restrict__ ws) {
    const int t = threadIdx.x & 63;              // lane 0..63
    const int wid = threadIdx.x >> 6;            // wave 0..3
    const int b = blockIdx.y;
    const int r0 = (blockIdx.x * WPB + wid) * STRIP;
    const float* __restrict__ p1 = img1 + (size_t)b * (IMG_H * IMG_W);
    const float* __restrict__ p2 = img2 + (size_t)b * (IMG_H * IMG_W);
    const int c8 = 8 * t;                        // lane owns cols c8..c8+7

    float cs[4][8];                              // ch: u, v, uu, vv
#pragma unroll
    for (int ch = 0; ch < 4; ++ch)
#pragma unroll
        for (int j = 0; j < 8; ++j) cs[ch][j] = 0.0f;

    auto addR = [&](float4 xa, float4 xb, float4 ya, float4 yb) {
        float xs[8] = {xa.x, xa.y, xa.z, xa.w, xb.x, xb.y, xb.z, xb.w};
        float ys[8] = {ya.x, ya.y, ya.z, ya.w, yb.x, yb.y, yb.z, yb.w};
#pragma unroll
        for (int j = 0; j < 8; ++j) {
            float u = xs[j] + ys[j], v = xs[j] - ys[j];
            cs[0][j] += u;                   cs[1][j] += v;
            cs[2][j] = fmaf(u, u, cs[2][j]); cs[3][j] = fmaf(v, v, cs[3][j]);
        }
    };
    auto subR = [&](float4 xa, float4 xb, float4 ya, float4 yb) {
        float xs[8] = {xa.x, xa.y, xa.z, xa.w, xb.x, xb.y, xb.z, xb.w};
        float ys[8] = {ya.x, ya.y, ya.z, ya.w, yb.x, yb.y, yb.z, yb.w};
#pragma unroll
        for (int j = 0; j < 8; ++j) {
            float u = xs[j] + ys[j], v = xs[j] - ys[j];
            cs[0][j] -= u;                    cs[1][j] -= v;
            cs[2][j] = fmaf(-u, u, cs[2][j]); cs[3][j] = fmaf(-v, v, cs[3][j]);
        }
    };

    // Warm vertical window for output row r0 (zero pad above the image).
    {
        int rlo = r0 - 5; if (rlo < 0) rlo = 0;
        const int rhi = r0 + 5;                  // r0 <= 504 -> rhi <= 509
        for (int r = rlo; r <= rhi; ++r) {
            const float* a1 = p1 + (size_t)r * IMG_W + c8;
            const float* a2 = p2 + (size_t)r * IMG_W + c8;
            addR(*(const float4*)a1, *(const float4*)(a1 + 4),
                 *(const float4*)a2, *(const float4*)(a2 + 4));
        }
    }

    // Prefetched add-row (row rn+5, clamped; consume guard applies bounds).
    float4 fxa, fxb, fya, fyb;
    auto prefetchAdd = [&](int rn) {
        int ra = rn + 5; if (ra > IMG_H - 1) ra = IMG_H - 1;
        const float* a1 = p1 + (size_t)ra * IMG_W + c8;
        const float* a2 = p2 + (size_t)ra * IMG_W + c8;
        fxa = *(const float4*)a1; fxb = *(const float4*)(a1 + 4);
        fya = *(const float4*)a2; fyb = *(const float4*)(a2 + 4);
    };

    const float mL = (t > 0)  ? 1.0f : 0.0f;     // zero shfl_up at lane 0
    const float mR = (t < 63) ? 1.0f : 0.0f;     // zero shfl_down at lane 63
    constexpr float inv  = 1.0f / 121.0f;
    constexpr float inv2 = 0.5f / 121.0f;
    constexpr float C1c = 0.01f * 0.01f;
    constexpr float C2c = 0.03f * 0.03f;
    float acc = 0.0f;

    prefetchAdd(r0 + 1);

    for (int i = 0; i < STRIP; ++i) {
        // --- horizontal 11-tap windows for row r0+i, all in registers ---
        float W[4][8];
#pragma unroll
        for (int ch = 0; ch < 4; ++ch) {
            float s0 = cs[ch][0], s1 = cs[ch][1], s2 = cs[ch][2], s3 = cs[ch][3];
            float s4 = cs[ch][4], s5 = cs[ch][5], s6 = cs[ch][6], s7 = cs[ch][7];
            float P2 = s0 + s1, P3 = P2 + s2, P4 = P3 + s3, P5 = P4 + s4;
            float P6 = P5 + s5, P7 = P6 + s6, P8 = P7 + s7;
            float Q2 = s7 + s6, Q3 = Q2 + s5, Q4 = Q3 + s4, Q5 = Q4 + s3;
            // from left neighbor: its suffix sums (cols 8t-5..8t-1 etc.)
            float Lq1 = __shfl_up(s7, 1), Lq2 = __shfl_up(Q2, 1),
                  Lq3 = __shfl_up(Q3, 1), Lq4 = __shfl_up(Q4, 1),
                  Lq5 = __shfl_up(Q5, 1);
            // from right neighbor: its prefix sums (cols 8t+8.. etc.)
            float Rp1 = __shfl_down(s0, 1), Rp2 = __shfl_down(P2, 1),
                  Rp3 = __shfl_down(P3, 1), Rp4 = __shfl_down(P4, 1),
                  Rp5 = __shfl_down(P5, 1);
            W[ch][0] = fmaf(Lq5, mL, P6);                    // cols 8t-5..8t+5
            W[ch][1] = fmaf(Lq4, mL, P7);
            W[ch][2] = fmaf(Lq3, mL, P8);
            W[ch][3] = fmaf(Rp1, mR, fmaf(Lq2, mL, P8));
            W[ch][4] = fmaf(Rp2, mR, fmaf(Lq1, mL, P8));
            W[ch][5] = fmaf(Rp3, mR, P8);
            W[ch][6] = fmaf(Rp4, mR, P8 - s0);
            W[ch][7] = fmaf(Rp5, mR, P8 - P2);               // cols 8t+2..8t+12
        }

        // Issue sub-row loads now; SSIM math below covers their latency
        // (at 16 waves/CU the combined SSIM issue of co-resident waves
        // exceeds L3-hit latency).
        const int rn = r0 + i + 1;
        const bool last = (i == STRIP - 1);
        const bool doSub = !last && (rn - 6 >= 0);           // wave-uniform
        float4 sxa, sxb, sya, syb;
        if (doSub) {
            const float* a1 = p1 + (size_t)(rn - 6) * IMG_W + c8;
            const float* a2 = p2 + (size_t)(rn - 6) * IMG_W + c8;
            sxa = *(const float4*)a1; sxb = *(const float4*)(a1 + 4);
            sya = *(const float4*)a2; syb = *(const float4*)(a2 + 4);
        }

        // --- SSIM for the 8 pixels this lane owns in row r0+i ---
#pragma unroll
        for (int j = 0; j < 8; ++j) {
            float mu_u = W[0][j] * inv, mu_v = W[1][j] * inv;
            float uu = mu_u * mu_u, vv = mu_v * mu_v;
            float Pq = 0.5f * (uu + vv);                    // mu1^2 + mu2^2
            float Mq = 0.5f * (uu - vv);                    // 2*mu1*mu2
            float A = fmaf(W[2][j] + W[3][j], inv2, -Pq);   // sig1^2+sig2^2
            float B = fmaf(W[2][j] - W[3][j], inv2, -Mq);   // 2*sig12
            acc += __fdividef((Mq + C1c) * (B + C2c), (Pq + C1c) * (A + C2c));
        }

        // --- advance vertical window to row rn (tail; wave-uniform) ---
        if (!last) {
            if (rn + 5 < IMG_H) addR(fxa, fxb, fya, fyb);   // prefetched 1 iter ago
            if (doSub)          subR(sxa, sxb, sya, syb);
            if (i < STRIP - 2)  prefetchAdd(rn + 1);        // in flight across
        }                                                   // next row's SSIM
    }

    // Reduce: intra-wave shuffle tree -> one atomic per wave.
#pragma unroll
    for (int off = 32; off > 0; off >>= 1) acc += __shfl_down(acc, off);
    if (t == 0) atomicAdd(ws, acc);
}

__global__ void ssim_finalize(const float* __restrict__ ws, float* __restrict__ out) {
    constexpr float inv_n = 1.0f / (float)((size_t)N_IMG * IMG_H * IMG_W);
    out[0] = 1.0f - ws[0] * inv_n;
}

extern "C" void kernel_launch(void* const* d_in, const int* in_sizes, int n_in,
                              void* d_out, int out_size, void* d_ws, size_t ws_size,
                              hipStream_t stream) {
    const float* img1 = (const float*)d_in[0];
    const float* img2 = (const float*)d_in[1];
    float* out = (float*)d_out;
    float* ws = (float*)d_ws;

    hipMemsetAsync(ws, 0, sizeof(float), stream);

    // (512/8 strips) / 4 waves = 16 groups x 64 images = 1024 blocks,
    // 4 blocks/CU x 4 waves = 16 waves/CU resident.
    dim3 grid(IMG_H / STRIP / WPB, N_IMG);
    ssim_kernel<<<grid, NTHREADS, 0, stream>>>(img1, img2, ws);
    ssim_finalize<<<1, 1, 0, stream>>>(ws, out);
}

// Round 8
// 216.130 us; speedup vs baseline: 1.2047x; 1.2047x over previous
//
#include <hip/hip_runtime.h>

// SSIM loss, fused. R13: R12 (4 waves/block packing of the register+shuffle
// kernel) with the REGISTER BUDGET fixed: __launch_bounds__(256, 2).
// R12 post-mortem: (256,4) capped VGPR at 64 (empirical session rule:
// cap ~= 256 / second-arg) -> the 76-reg working set spilled ~12 regs/lane
// (WRITE_SIZE 158MB, FETCH +70MB) -> 158us despite occupancy 37%.
// The residency theory itself was CONFIRMED (occ 23->37, hbm 1800->2800);
// only the spill tax ate the win. (256,2) -> 128 cap, needs ~76 -> no spill,
// 16 waves/CU still resident (1024 blocks = 4/CU x 4 waves, VGPR allows 6/SIMD).
// Kernel body IDENTICAL to R11/R12 (absmax 0.0 both):
//  - zero LDS, zero barriers; lane owns 8 adjacent cols (2 float4/img);
//  - cs[4][8] column sums in registers; u=x+y, v=x-y -> Su,Sv,Suu,Svv;
//  - 11-tap window = local prefix/suffix sums + 5 shfl_up + 5 shfl_down,
//    edges via mask-fma;
//  - add-row prefetched one iteration ahead; sub-row issued before SSIM math.

#define IMG_H 512
#define IMG_W 512
#define N_IMG 64
#define STRIP 8            // output rows per wave
#define NTHREADS 256       // 4 independent waves per block
#define WPB 4              // waves per block

__global__ __launch_bounds__(NTHREADS, 2) void ssim_kernel(const float* __restrict__ img1,
                                                           const float* __restrict__ img2,
                                                           float* __restrict__ ws) {
    const int t = threadIdx.x & 63;              // lane 0..63
    const int wid = threadIdx.x >> 6;            // wave 0..3
    const int b = blockIdx.y;
    const int r0 = (blockIdx.x * WPB + wid) * STRIP;
    const float* __restrict__ p1 = img1 + (size_t)b * (IMG_H * IMG_W);
    const float* __restrict__ p2 = img2 + (size_t)b * (IMG_H * IMG_W);
    const int c8 = 8 * t;                        // lane owns cols c8..c8+7

    float cs[4][8];                              // ch: u, v, uu, vv
#pragma unroll
    for (int ch = 0; ch < 4; ++ch)
#pragma unroll
        for (int j = 0; j < 8; ++j) cs[ch][j] = 0.0f;

    auto addR = [&](float4 xa, float4 xb, float4 ya, float4 yb) {
        float xs[8] = {xa.x, xa.y, xa.z, xa.w, xb.x, xb.y, xb.z, xb.w};
        float ys[8] = {ya.x, ya.y, ya.z, ya.w, yb.x, yb.y, yb.z, yb.w};
#pragma unroll
        for (int j = 0; j < 8; ++j) {
            float u = xs[j] + ys[j], v = xs[j] - ys[j];
            cs[0][j] += u;                   cs[1][j] += v;
            cs[2][j] = fmaf(u, u, cs[2][j]); cs[3][j] = fmaf(v, v, cs[3][j]);
        }
    };
    auto subR = [&](float4 xa, float4 xb, float4 ya, float4 yb) {
        float xs[8] = {xa.x, xa.y, xa.z, xa.w, xb.x, xb.y, xb.z, xb.w};
        float ys[8] = {ya.x, ya.y, ya.z, ya.w, yb.x, yb.y, yb.z, yb.w};
#pragma unroll
        for (int j = 0; j < 8; ++j) {
            float u = xs[j] + ys[j], v = xs[j] - ys[j];
            cs[0][j] -= u;                    cs[1][j] -= v;
            cs[2][j] = fmaf(-u, u, cs[2][j]); cs[3][j] = fmaf(-v, v, cs[3][j]);
        }
    };

    // Warm vertical window for output row r0 (zero pad above the image).
    {
        int rlo = r0 - 5; if (rlo < 0) rlo = 0;
        const int rhi = r0 + 5;                  // r0 <= 504 -> rhi <= 509
        for (int r = rlo; r <= rhi; ++r) {
            const float* a1 = p1 + (size_t)r * IMG_W + c8;
            const float* a2 = p2 + (size_t)r * IMG_W + c8;
            addR(*(const float4*)a1, *(const float4*)(a1 + 4),
                 *(const float4*)a2, *(const float4*)(a2 + 4));
        }
    }

    // Prefetched add-row (row rn+5, clamped; consume guard applies bounds).
    float4 fxa, fxb, fya, fyb;
    auto prefetchAdd = [&](int rn) {
        int ra = rn + 5; if (ra > IMG_H - 1) ra = IMG_H - 1;
        const float* a1 = p1 + (size_t)ra * IMG_W + c8;
        const float* a2 = p2 + (size_t)ra * IMG_W + c8;
        fxa = *(const float4*)a1; fxb = *(const float4*)(a1 + 4);
        fya = *(const float4*)a2; fyb = *(const float4*)(a2 + 4);
    };

    const float mL = (t > 0)  ? 1.0f : 0.0f;     // zero shfl_up at lane 0
    const float mR = (t < 63) ? 1.0f : 0.0f;     // zero shfl_down at lane 63
    constexpr float inv  = 1.0f / 121.0f;
    constexpr float inv2 = 0.5f / 121.0f;
    constexpr float C1c = 0.01f * 0.01f;
    constexpr float C2c = 0.03f * 0.03f;
    float acc = 0.0f;

    prefetchAdd(r0 + 1);

    for (int i = 0; i < STRIP; ++i) {
        // --- horizontal 11-tap windows for row r0+i, all in registers ---
        float W[4][8];
#pragma unroll
        for (int ch = 0; ch < 4; ++ch) {
            float s0 = cs[ch][0], s1 = cs[ch][1], s2 = cs[ch][2], s3 = cs[ch][3];
            float s4 = cs[ch][4], s5 = cs[ch][5], s6 = cs[ch][6], s7 = cs[ch][7];
            float P2 = s0 + s1, P3 = P2 + s2, P4 = P3 + s3, P5 = P4 + s4;
            float P6 = P5 + s5, P7 = P6 + s6, P8 = P7 + s7;
            float Q2 = s7 + s6, Q3 = Q2 + s5, Q4 = Q3 + s4, Q5 = Q4 + s3;
            // from left neighbor: its suffix sums (cols 8t-5..8t-1 etc.)
            float Lq1 = __shfl_up(s7, 1), Lq2 = __shfl_up(Q2, 1),
                  Lq3 = __shfl_up(Q3, 1), Lq4 = __shfl_up(Q4, 1),
                  Lq5 = __shfl_up(Q5, 1);
            // from right neighbor: its prefix sums (cols 8t+8.. etc.)
            float Rp1 = __shfl_down(s0, 1), Rp2 = __shfl_down(P2, 1),
                  Rp3 = __shfl_down(P3, 1), Rp4 = __shfl_down(P4, 1),
                  Rp5 = __shfl_down(P5, 1);
            W[ch][0] = fmaf(Lq5, mL, P6);                    // cols 8t-5..8t+5
            W[ch][1] = fmaf(Lq4, mL, P7);
            W[ch][2] = fmaf(Lq3, mL, P8);
            W[ch][3] = fmaf(Rp1, mR, fmaf(Lq2, mL, P8));
            W[ch][4] = fmaf(Rp2, mR, fmaf(Lq1, mL, P8));
            W[ch][5] = fmaf(Rp3, mR, P8);
            W[ch][6] = fmaf(Rp4, mR, P8 - s0);
            W[ch][7] = fmaf(Rp5, mR, P8 - P2);               // cols 8t+2..8t+12
        }

        // Issue sub-row loads now; SSIM math below covers their latency.
        const int rn = r0 + i + 1;
        const bool last = (i == STRIP - 1);
        const bool doSub = !last && (rn - 6 >= 0);           // wave-uniform
        float4 sxa, sxb, sya, syb;
        if (doSub) {
            const float* a1 = p1 + (size_t)(rn - 6) * IMG_W + c8;
            const float* a2 = p2 + (size_t)(rn - 6) * IMG_W + c8;
            sxa = *(const float4*)a1; sxb = *(const float4*)(a1 + 4);
            sya = *(const float4*)a2; syb = *(const float4*)(a2 + 4);
        }

        // --- SSIM for the 8 pixels this lane owns in row r0+i ---
#pragma unroll
        for (int j = 0; j < 8; ++j) {
            float mu_u = W[0][j] * inv, mu_v = W[1][j] * inv;
            float uu = mu_u * mu_u, vv = mu_v * mu_v;
            float Pq = 0.5f * (uu + vv);                    // mu1^2 + mu2^2
            float Mq = 0.5f * (uu - vv);                    // 2*mu1*mu2
            float A = fmaf(W[2][j] + W[3][j], inv2, -Pq);   // sig1^2+sig2^2
            float B = fmaf(W[2][j] - W[3][j], inv2, -Mq);   // 2*sig12
            acc += __fdividef((Mq + C1c) * (B + C2c), (Pq + C1c) * (A + C2c));
        }

        // --- advance vertical window to row rn (tail; wave-uniform) ---
        if (!last) {
            if (rn + 5 < IMG_H) addR(fxa, fxb, fya, fyb);   // prefetched 1 iter ago
            if (doSub)          subR(sxa, sxb, sya, syb);
            if (i < STRIP - 2)  prefetchAdd(rn + 1);        // in flight across
        }                                                   // next row's SSIM
    }

    // Reduce: intra-wave shuffle tree -> one atomic per wave.
#pragma unroll
    for (int off = 32; off > 0; off >>= 1) acc += __shfl_down(acc, off);
    if (t == 0) atomicAdd(ws, acc);
}

__global__ void ssim_finalize(const float* __restrict__ ws, float* __restrict__ out) {
    constexpr float inv_n = 1.0f / (float)((size_t)N_IMG * IMG_H * IMG_W);
    out[0] = 1.0f - ws[0] * inv_n;
}

extern "C" void kernel_launch(void* const* d_in, const int* in_sizes, int n_in,
                              void* d_out, int out_size, void* d_ws, size_t ws_size,
                              hipStream_t stream) {
    const float* img1 = (const float*)d_in[0];
    const float* img2 = (const float*)d_in[1];
    float* out = (float*)d_out;
    float* ws = (float*)d_ws;

    hipMemsetAsync(ws, 0, sizeof(float), stream);

    // (512/8 strips) / 4 waves = 16 groups x 64 images = 1024 blocks,
    // 4 blocks/CU x 4 waves = 16 waves/CU resident, single generation.
    dim3 grid(IMG_H / STRIP / WPB, N_IMG);
    ssim_kernel<<<grid, NTHREADS, 0, stream>>>(img1, img2, ws);
    ssim_finalize<<<1, 1, 0, stream>>>(ws, out);
}

// Round 9
// 187.295 us; speedup vs baseline: 1.3902x; 1.1540x over previous
//
#include <hip/hip_runtime.h>

// SSIM loss, fused. R14: R10 with the DS-PIPE LOAD CUT 1.7x.
// Unifying theory after R10-R13: every variant saturates the per-CU LDS/DS
// pipe (~6M wave-ops/dispatch ~= 56us at b32 throughput ~5.8cy) - shuffles
// (ds_bpermute) and ds_reads share it, which is why LDS-staged (85us) and
// shuffle (114us) kernels plateau together and extra waves don't help.
// R14: re-assign each thread the ADJACENT pixel pair (2t, 2t+1) instead of
// (t, t+128). Their 11-tap windows overlap: per channel the union of both
// pixels' S-reads is {2t+3} + b64@{2t+12 or 2t+4 by parity} + {2t+14}, and
// both share the SAME two Q reads -> 5 ds-ops per 2px per ch (was 10).
// Per-pixel arithmetic is BIT-IDENTICAL to R5/R10:
//   W0 = ((rA + rBC.x) + (rBC.y + qlo)) + qhi
//   W1 = ((rBC.x + rBC.y) + (rD + qlo)) + qhi
// (both parities reduce to these same expressions; verified vs rho-table).
// DS ops/thread-row: 48 -> 28 -> DS-pipe time ~56us -> ~33us.
// Geometry, halo, warm-up, pipeline order (consume -> prefetch -> writeSQ
// -> hphase -> barrier), barriers, reduction: R10 verbatim.

#define IMG_H 512
#define IMG_W 512
#define N_IMG 64
#define STRIP 32           // rows per block
#define BCOLS 256          // output cols per block
#define NTHREADS 128
#define SSZ 272            // S: idx = cl + 8, cl in [-8, 263] (pads zero)
#define QSZ 68             // Q: idx = m + 2,  m in [-2, 65]  (pads zero)
#define ROWSZ (SSZ + QSZ)  // 340 floats per [buf][ch] (mult of 4 -> 16B align)

__global__ __launch_bounds__(NTHREADS) void ssim_kernel(const float* __restrict__ img1,
                                                        const float* __restrict__ img2,
                                                        float* __restrict__ ws) {
    __shared__ __align__(16) float V[2][4][ROWSZ];  // double buffer; ch: u,v,uu,vv
    __shared__ float wsum[2];
    const int t = threadIdx.x;
    const int b = blockIdx.y;
    const int sx = blockIdx.x >> 1;      // row-strip index
    const int half = blockIdx.x & 1;     // column half
    const int r0 = sx * STRIP;
    const int cbase = half * BCOLS;
    const float* __restrict__ p1 = img1 + (size_t)b * (IMG_H * IMG_W);
    const float* __restrict__ p2 = img2 + (size_t)b * (IMG_H * IMG_W);

    // Zero all of V once; pad regions are never written after this.
    for (int i = t; i < 2 * 4 * ROWSZ; i += NTHREADS) (&V[0][0][0])[i] = 0.0f;

    // Main cols: lane owns img cols cm, cm+1. Halo cols: threads 0..7 own
    // one extra pair just outside [cbase, cbase+255] (zero-pad if outside
    // the image; S/Q for invalid sides stay 0 from the init above).
    const int cm = cbase + 2 * t;
    const int hloc = (t < 4) ? (-8 + 2 * t) : (256 + 2 * (t - 4));  // local
    const int hcol = cbase + hloc;                                   // image
    const bool hval = (t < 8) && (hcol >= 0) && (hcol <= IMG_W - 2);

    float cs[4][2], csH[4][2];
#pragma unroll
    for (int ch = 0; ch < 4; ++ch)
#pragma unroll
        for (int j = 0; j < 2; ++j) { cs[ch][j] = 0.0f; csH[ch][j] = 0.0f; }

    auto addPair = [&](float (&a)[4][2], float2 x, float2 y) {
#pragma unroll
        for (int j = 0; j < 2; ++j) {
            float xv = j ? x.y : x.x, yv = j ? y.y : y.x;
            float u = xv + yv, v = xv - yv;
            a[0][j] += u;                   a[1][j] += v;
            a[2][j] = fmaf(u, u, a[2][j]);  a[3][j] = fmaf(v, v, a[3][j]);
        }
    };
    auto subPair = [&](float (&a)[4][2], float2 x, float2 y) {
#pragma unroll
        for (int j = 0; j < 2; ++j) {
            float xv = j ? x.y : x.x, yv = j ? y.y : y.x;
            float u = xv + yv, v = xv - yv;
            a[0][j] -= u;                   a[1][j] -= v;
            a[2][j] = fmaf(-u, u, a[2][j]); a[3][j] = fmaf(-v, v, a[3][j]);
        }
    };

    // Warm vertical window for output row r0 (zero pad above the image).
    {
        int rlo = r0 - 5; if (rlo < 0) rlo = 0;
        const int rhi = r0 + 5;          // r0 <= 480 -> rhi <= 485 < 512
        for (int r = rlo; r <= rhi; ++r) {
            float2 x = *(const float2*)(p1 + (size_t)r * IMG_W + cm);
            float2 y = *(const float2*)(p2 + (size_t)r * IMG_W + cm);
            addPair(cs, x, y);
            if (hval) {
                float2 hx = *(const float2*)(p1 + (size_t)r * IMG_W + hcol);
                float2 hy = *(const float2*)(p2 + (size_t)r * IMG_W + hcol);
                addPair(csH, hx, hy);
            }
        }
    }

    // Prefetch registers: rows to advance the window to row rn
    // (add rn+5, subtract rn-6). Row-clamped unconditional main loads;
    // consume() applies the real boundary conditions.
    float2 pax, pay, psx, psy, hax, hay, hsx, hsy;
    auto prefetch = [&](int rn) {
        int ra = rn + 5; if (ra > IMG_H - 1) ra = IMG_H - 1;
        int rs = rn - 6; if (rs < 0) rs = 0;
        pax = *(const float2*)(p1 + (size_t)ra * IMG_W + cm);
        pay = *(const float2*)(p2 + (size_t)ra * IMG_W + cm);
        psx = *(const float2*)(p1 + (size_t)rs * IMG_W + cm);
        psy = *(const float2*)(p2 + (size_t)rs * IMG_W + cm);
        if (hval) {
            hax = *(const float2*)(p1 + (size_t)ra * IMG_W + hcol);
            hay = *(const float2*)(p2 + (size_t)ra * IMG_W + hcol);
            hsx = *(const float2*)(p1 + (size_t)rs * IMG_W + hcol);
            hsy = *(const float2*)(p2 + (size_t)rs * IMG_W + hcol);
        }
    };
    auto consume = [&](int rn) {
        if (rn + 5 < IMG_H) {   // block-uniform
            addPair(cs, pax, pay);
            if (hval) addPair(csH, hax, hay);
        }
        if (rn - 6 >= 0) {      // block-uniform
            subPair(cs, psx, psy);
            if (hval) subPair(csH, hsx, hsy);
        }
    };

    auto writeSQ = [&](int p) {
#pragma unroll
        for (int ch = 0; ch < 4; ++ch) {
            *(float2*)&V[p][ch][8 + 2 * t] = make_float2(cs[ch][0], cs[ch][1]);
            float ps = cs[ch][0] + cs[ch][1];
            float nb = __shfl_down(ps, 1);
            if ((t & 1) == 0) V[p][ch][SSZ + 2 + (t >> 1)] = ps + nb;  // m = t/2
            // Halo S + halo quads m=-2,-1 (idx 0,1) and m=64,65 (idx 66,67).
            float psH = csH[ch][0] + csH[ch][1];
            float nbH = __shfl_down(psH, 1);
            if (t < 8) {
                *(float2*)&V[p][ch][8 + hloc] = make_float2(csH[ch][0], csH[ch][1]);
                if ((t & 1) == 0) {
                    const int qi = (t < 4) ? (t >> 1) : (64 + (t >> 1));
                    V[p][ch][SSZ + qi] = psH + nbH;
                }
            }
        }
    };

    // --- H phase offsets: thread owns ADJACENT px pair (2t, 2t+1) ---
    // S union by parity of t:
    //   t even (rho 0/1): b32@2t+3, b64@2t+12, b32@2t+14, Q(m-1),Q(m), m=t/2
    //   t odd  (rho 2/3): b32@2t+3, b64@2t+4,  b32@2t+14, Q(m'),Q(m'+1)
    // Both reduce to the SAME combine expressions (bit-identical to R5/R10).
    const int iA = 2 * t + 3;
    const int iBC = (t & 1) ? (2 * t + 4) : (2 * t + 12);
    const int iD = 2 * t + 14;
    const int iQ = SSZ + 1 + (t >> 1) + (t & 1);   // qlo; qhi = iQ+1

    __syncthreads();          // LDS zeroing complete
    writeSQ(0);               // S/Q for row r0 into buf 0
    prefetch(r0 + 1);         // prologue-only exposed drain
    __syncthreads();          // buf 0 visible

    constexpr float inv  = 1.0f / 121.0f;
    constexpr float inv2 = 0.5f / 121.0f;
    constexpr float C1c = 0.01f * 0.01f;
    constexpr float C2c = 0.03f * 0.03f;
    float acc = 0.0f;

    auto hphase = [&](int p) {
        float W0[4], W1[4];
#pragma unroll
        for (int ch = 0; ch < 4; ++ch) {
            const float* __restrict__ Vf = &V[p][ch][0];
            float rA = Vf[iA];
            float2 rBC = *(const float2*)&Vf[iBC];
            float rD = Vf[iD];
            float qlo = Vf[iQ], qhi = Vf[iQ + 1];
            W0[ch] = ((rA + rBC.x) + (rBC.y + qlo)) + qhi;
            W1[ch] = ((rBC.x + rBC.y) + (rD + qlo)) + qhi;
        }
#pragma unroll
        for (int k = 0; k < 2; ++k) {
            const float* W = k ? W1 : W0;
            float mu_u = W[0] * inv, mu_v = W[1] * inv;
            float uu = mu_u * mu_u, vv = mu_v * mu_v;
            float P = 0.5f * (uu + vv);             // mu1^2 + mu2^2
            float M = 0.5f * (uu - vv);             // 2*mu1*mu2
            float A = fmaf(W[2] + W[3], inv2, -P);  // sig1^2 + sig2^2
            float B = fmaf(W[2] - W[3], inv2, -M);  // 2*sig12
            float num = (M + C1c) * (B + C2c);
            float den = (P + C1c) * (A + C2c);
            acc += __fdividef(num, den);
        }
    };

    // Main pipeline (R9/R10's proven order), one barrier per row:
    //   consume(i+1): loads issued one full iteration ago (done);
    //   prefetch(i+2): then writeSQ + hphase run before the barrier's
    //                  vmcnt(0) -> drain is free;
    //   writeSQ(i+1) -> buf !p; hphase(i) -> buf p (disjoint, no WAR).
    for (int i = 0; i < STRIP - 1; ++i) {
        consume(r0 + i + 1);
        int rn = r0 + i + 2;                           // clamped redundant
        if (rn > r0 + STRIP - 1) rn = r0 + STRIP - 1;  // load on last iter
        prefetch(rn);
        writeSQ((i + 1) & 1);
        hphase(i & 1);
        __syncthreads();
    }
    hphase((STRIP - 1) & 1);      // last row

    // Reduce: wave shuffle -> LDS -> one atomic per block.
#pragma unroll
    for (int off = 32; off > 0; off >>= 1) acc += __shfl_down(acc, off);
    if ((t & 63) == 0) wsum[t >> 6] = acc;
    __syncthreads();
    if (t == 0) atomicAdd(ws, wsum[0] + wsum[1]);
}

__global__ void ssim_finalize(const float* __restrict__ ws, float* __restrict__ out) {
    constexpr float inv_n = 1.0f / (float)((size_t)N_IMG * IMG_H * IMG_W);
    out[0] = 1.0f - ws[0] * inv_n;
}

extern "C" void kernel_launch(void* const* d_in, const int* in_sizes, int n_in,
                              void* d_out, int out_size, void* d_ws, size_t ws_size,
                              hipStream_t stream) {
    const float* img1 = (const float*)d_in[0];
    const float* img2 = (const float*)d_in[1];
    float* out = (float*)d_out;
    float* ws = (float*)d_ws;

    hipMemsetAsync(ws, 0, sizeof(float), stream);

    // (16 row-strips x 2 col-halves, 64 images) = 2048 blocks = 8/CU,
    // single generation (LDS 11.3KB -> 14/CU possible).
    dim3 grid((IMG_H / STRIP) * 2, N_IMG);
    ssim_kernel<<<grid, NTHREADS, 0, stream>>>(img1, img2, ws);
    ssim_finalize<<<1, 1, 0, stream>>>(ws, out);
}

// Round 10
// 186.860 us; speedup vs baseline: 1.3934x; 1.0023x over previous
//
#include <hip/hip_runtime.h>

// SSIM loss, fused. R15: R14 with ONE change — the main-loop barrier no
// longer drains vmcnt.
// R14 post-mortem: cutting DS ops 1.7x changed nothing (85us both) ->
// DS-pipe theory refuted. Surviving theory: __syncthreads() compiles to
// s_waitcnt vmcnt(0) lgkmcnt(0) + s_barrier, so ANY load issued in
// iteration i is force-drained at iteration i's barrier -> every row pays
// (HBM latency ~900cy) - (intra-iteration cover ~300cy) exposed, and all
// phase-locked blocks stall together: 6600cy/row measured vs ~500cy issued.
// R15: main-loop barrier = asm("s_waitcnt lgkmcnt(0)") + raw s_barrier
// (the guide's T3/T4 idiom: loads stay in flight ACROSS barriers).
//  - LDS correctness: lgkmcnt(0) makes writeSQ's ds_writes visible to the
//    sibling wave before s_barrier; "memory" clobber pins memory-op order.
//  - Prefetch loads (register destinations, no LDS interaction) cross the
//    barrier and get a FULL iteration of cover (>1500cy > ~900cy HBM);
//    the compiler still emits the correct counted vmcnt before consume.
//  - Epilogue reduction keeps a real __syncthreads() (one final drain ok).
// Everything else R14 verbatim: adjacent-pair H phase (5 ds-ops/2px/ch),
// u/v channel algebra, halo scheme, pipeline order consume -> prefetch ->
// writeSQ -> hphase -> barrier. Per-pixel arithmetic bit-identical (absmax
// 0.0 expected).

#define IMG_H 512
#define IMG_W 512
#define N_IMG 64
#define STRIP 32           // rows per block
#define BCOLS 256          // output cols per block
#define NTHREADS 128
#define SSZ 272            // S: idx = cl + 8, cl in [-8, 263] (pads zero)
#define QSZ 68             // Q: idx = m + 2,  m in [-2, 65]  (pads zero)
#define ROWSZ (SSZ + QSZ)  // 340 floats per [buf][ch] (mult of 4 -> 16B align)

// Barrier WITHOUT the vmcnt(0) drain: LDS ops complete, vmem stays in flight.
#define BARRIER_NODRAIN()                                   \
    do {                                                    \
        asm volatile("s_waitcnt lgkmcnt(0)" ::: "memory");  \
        __builtin_amdgcn_s_barrier();                       \
    } while (0)

__global__ __launch_bounds__(NTHREADS) void ssim_kernel(const float* __restrict__ img1,
                                                        const float* __restrict__ img2,
                                                        float* __restrict__ ws) {
    __shared__ __align__(16) float V[2][4][ROWSZ];  // double buffer; ch: u,v,uu,vv
    __shared__ float wsum[2];
    const int t = threadIdx.x;
    const int b = blockIdx.y;
    const int sx = blockIdx.x >> 1;      // row-strip index
    const int half = blockIdx.x & 1;     // column half
    const int r0 = sx * STRIP;
    const int cbase = half * BCOLS;
    const float* __restrict__ p1 = img1 + (size_t)b * (IMG_H * IMG_W);
    const float* __restrict__ p2 = img2 + (size_t)b * (IMG_H * IMG_W);

    // Zero all of V once; pad regions are never written after this.
    for (int i = t; i < 2 * 4 * ROWSZ; i += NTHREADS) (&V[0][0][0])[i] = 0.0f;

    // Main cols: lane owns img cols cm, cm+1. Halo cols: threads 0..7 own
    // one extra pair just outside [cbase, cbase+255] (zero-pad if outside
    // the image; S/Q for invalid sides stay 0 from the init above).
    const int cm = cbase + 2 * t;
    const int hloc = (t < 4) ? (-8 + 2 * t) : (256 + 2 * (t - 4));  // local
    const int hcol = cbase + hloc;                                   // image
    const bool hval = (t < 8) && (hcol >= 0) && (hcol <= IMG_W - 2);

    float cs[4][2], csH[4][2];
#pragma unroll
    for (int ch = 0; ch < 4; ++ch)
#pragma unroll
        for (int j = 0; j < 2; ++j) { cs[ch][j] = 0.0f; csH[ch][j] = 0.0f; }

    auto addPair = [&](float (&a)[4][2], float2 x, float2 y) {
#pragma unroll
        for (int j = 0; j < 2; ++j) {
            float xv = j ? x.y : x.x, yv = j ? y.y : y.x;
            float u = xv + yv, v = xv - yv;
            a[0][j] += u;                   a[1][j] += v;
            a[2][j] = fmaf(u, u, a[2][j]);  a[3][j] = fmaf(v, v, a[3][j]);
        }
    };
    auto subPair = [&](float (&a)[4][2], float2 x, float2 y) {
#pragma unroll
        for (int j = 0; j < 2; ++j) {
            float xv = j ? x.y : x.x, yv = j ? y.y : y.x;
            float u = xv + yv, v = xv - yv;
            a[0][j] -= u;                   a[1][j] -= v;
            a[2][j] = fmaf(-u, u, a[2][j]); a[3][j] = fmaf(-v, v, a[3][j]);
        }
    };

    // Warm vertical window for output row r0 (zero pad above the image).
    {
        int rlo = r0 - 5; if (rlo < 0) rlo = 0;
        const int rhi = r0 + 5;          // r0 <= 480 -> rhi <= 485 < 512
        for (int r = rlo; r <= rhi; ++r) {
            float2 x = *(const float2*)(p1 + (size_t)r * IMG_W + cm);
            float2 y = *(const float2*)(p2 + (size_t)r * IMG_W + cm);
            addPair(cs, x, y);
            if (hval) {
                float2 hx = *(const float2*)(p1 + (size_t)r * IMG_W + hcol);
                float2 hy = *(const float2*)(p2 + (size_t)r * IMG_W + hcol);
                addPair(csH, hx, hy);
            }
        }
    }

    // Prefetch registers: rows to advance the window to row rn
    // (add rn+5, subtract rn-6). Row-clamped unconditional main loads;
    // consume() applies the real boundary conditions.
    float2 pax, pay, psx, psy, hax, hay, hsx, hsy;
    auto prefetch = [&](int rn) {
        int ra = rn + 5; if (ra > IMG_H - 1) ra = IMG_H - 1;
        int rs = rn - 6; if (rs < 0) rs = 0;
        pax = *(const float2*)(p1 + (size_t)ra * IMG_W + cm);
        pay = *(const float2*)(p2 + (size_t)ra * IMG_W + cm);
        psx = *(const float2*)(p1 + (size_t)rs * IMG_W + cm);
        psy = *(const float2*)(p2 + (size_t)rs * IMG_W + cm);
        if (hval) {
            hax = *(const float2*)(p1 + (size_t)ra * IMG_W + hcol);
            hay = *(const float2*)(p2 + (size_t)ra * IMG_W + hcol);
            hsx = *(const float2*)(p1 + (size_t)rs * IMG_W + hcol);
            hsy = *(const float2*)(p2 + (size_t)rs * IMG_W + hcol);
        }
    };
    auto consume = [&](int rn) {
        if (rn + 5 < IMG_H) {   // block-uniform
            addPair(cs, pax, pay);
            if (hval) addPair(csH, hax, hay);
        }
        if (rn - 6 >= 0) {      // block-uniform
            subPair(cs, psx, psy);
            if (hval) subPair(csH, hsx, hsy);
        }
    };

    auto writeSQ = [&](int p) {
#pragma unroll
        for (int ch = 0; ch < 4; ++ch) {
            *(float2*)&V[p][ch][8 + 2 * t] = make_float2(cs[ch][0], cs[ch][1]);
            float ps = cs[ch][0] + cs[ch][1];
            float nb = __shfl_down(ps, 1);
            if ((t & 1) == 0) V[p][ch][SSZ + 2 + (t >> 1)] = ps + nb;  // m = t/2
            // Halo S + halo quads m=-2,-1 (idx 0,1) and m=64,65 (idx 66,67).
            float psH = csH[ch][0] + csH[ch][1];
            float nbH = __shfl_down(psH, 1);
            if (t < 8) {
                *(float2*)&V[p][ch][8 + hloc] = make_float2(csH[ch][0], csH[ch][1]);
                if ((t & 1) == 0) {
                    const int qi = (t < 4) ? (t >> 1) : (64 + (t >> 1));
                    V[p][ch][SSZ + qi] = psH + nbH;
                }
            }
        }
    };

    // --- H phase offsets: thread owns ADJACENT px pair (2t, 2t+1) ---
    // S union by parity of t:
    //   t even (rho 0/1): b32@2t+3, b64@2t+12, b32@2t+14, Q(m-1),Q(m), m=t/2
    //   t odd  (rho 2/3): b32@2t+3, b64@2t+4,  b32@2t+14, Q(m'),Q(m'+1)
    // Both reduce to the SAME combine expressions (bit-identical to R5/R10).
    const int iA = 2 * t + 3;
    const int iBC = (t & 1) ? (2 * t + 4) : (2 * t + 12);
    const int iD = 2 * t + 14;
    const int iQ = SSZ + 1 + (t >> 1) + (t & 1);   // qlo; qhi = iQ+1

    BARRIER_NODRAIN();        // LDS zeroing complete
    writeSQ(0);               // S/Q for row r0 into buf 0
    prefetch(r0 + 1);         // loads may stay in flight across the barrier
    BARRIER_NODRAIN();        // buf 0 visible

    constexpr float inv  = 1.0f / 121.0f;
    constexpr float inv2 = 0.5f / 121.0f;
    constexpr float C1c = 0.01f * 0.01f;
    constexpr float C2c = 0.03f * 0.03f;
    float acc = 0.0f;

    auto hphase = [&](int p) {
        float W0[4], W1[4];
#pragma unroll
        for (int ch = 0; ch < 4; ++ch) {
            const float* __restrict__ Vf = &V[p][ch][0];
            float rA = Vf[iA];
            float2 rBC = *(const float2*)&Vf[iBC];
            float rD = Vf[iD];
            float qlo = Vf[iQ], qhi = Vf[iQ + 1];
            W0[ch] = ((rA + rBC.x) + (rBC.y + qlo)) + qhi;
            W1[ch] = ((rBC.x + rBC.y) + (rD + qlo)) + qhi;
        }
#pragma unroll
        for (int k = 0; k < 2; ++k) {
            const float* W = k ? W1 : W0;
            float mu_u = W[0] * inv, mu_v = W[1] * inv;
            float uu = mu_u * mu_u, vv = mu_v * mu_v;
            float P = 0.5f * (uu + vv);             // mu1^2 + mu2^2
            float M = 0.5f * (uu - vv);             // 2*mu1*mu2
            float A = fmaf(W[2] + W[3], inv2, -P);  // sig1^2 + sig2^2
            float B = fmaf(W[2] - W[3], inv2, -M);  // 2*sig12
            float num = (M + C1c) * (B + C2c);
            float den = (P + C1c) * (A + C2c);
            acc += __fdividef(num, den);
        }
    };

    // Main pipeline, one NON-DRAINING barrier per row:
    //   consume(i+1): compiler-counted vmcnt wait on loads issued a full
    //                 iteration ago (now with >1500cy of cover, complete);
    //   prefetch(i+2): loads issued here CROSS the barrier and stay in
    //                  flight until next iteration's consume;
    //   writeSQ(i+1) -> buf !p; hphase(i) -> buf p (disjoint, no WAR);
    //   BARRIER_NODRAIN: lgkmcnt(0) only (ds_writes visible), no vmem drain.
    for (int i = 0; i < STRIP - 1; ++i) {
        consume(r0 + i + 1);
        int rn = r0 + i + 2;                           // clamped redundant
        if (rn > r0 + STRIP - 1) rn = r0 + STRIP - 1;  // load on last iter
        prefetch(rn);
        writeSQ((i + 1) & 1);
        hphase(i & 1);
        BARRIER_NODRAIN();
    }
    hphase((STRIP - 1) & 1);      // last row

    // Reduce: wave shuffle -> LDS -> one atomic per block.
    // Real __syncthreads here (single final drain is fine).
#pragma unroll
    for (int off = 32; off > 0; off >>= 1) acc += __shfl_down(acc, off);
    if ((t & 63) == 0) wsum[t >> 6] = acc;
    __syncthreads();
    if (t == 0) atomicAdd(ws, wsum[0] + wsum[1]);
}

__global__ void ssim_finalize(const float* __restrict__ ws, float* __restrict__ out) {
    constexpr float inv_n = 1.0f / (float)((size_t)N_IMG * IMG_H * IMG_W);
    out[0] = 1.0f - ws[0] * inv_n;
}

extern "C" void kernel_launch(void* const* d_in, const int* in_sizes, int n_in,
                              void* d_out, int out_size, void* d_ws, size_t ws_size,
                              hipStream_t stream) {
    const float* img1 = (const float*)d_in[0];
    const float* img2 = (const float*)d_in[1];
    float* out = (float*)d_out;
    float* ws = (float*)d_ws;

    hipMemsetAsync(ws, 0, sizeof(float), stream);

    // (16 row-strips x 2 col-halves, 64 images) = 2048 blocks = 8/CU,
    // single generation (LDS 11.3KB -> 14/CU possible).
    dim3 grid((IMG_H / STRIP) * 2, N_IMG);
    ssim_kernel<<<grid, NTHREADS, 0, stream>>>(img1, img2, ws);
    ssim_finalize<<<1, 1, 0, stream>>>(ws, out);
}